// Round 4
// baseline (493.575 us; speedup 1.0000x reference)
//
#include <hip/hip_runtime.h>
#include <cmath>

// DBRX router, fused single kernel, zero-LDS main loop.
// logits = x[16384,6144] @ W[6144,16]; softmax; top-4; L1-normalize.
// Outputs flat: weights fp32[16384*16] | top_weights fp32[16384*4] | experts(as float)[16384*4]
//
// Block = 8 waves = 64 tokens; wave wv owns d-slice [wv*768, (wv+1)*768).
// Wave lanes: r = lane>>2 (token row 0..15), m = lane&3 (d-quad within 16-d chunk).
// Lane loads x[t0+r+16*it][chunk + 4m .. +3] as float4 directly into FMAs (no LDS),
// holds W rows [chunk+4m .. +3] x 16 experts (64 floats) in regs, reused over 4 its.
// Both x and W register-double-buffered (chunk-pair loop). K-reduce: shfl_xor over m,
// then one epilogue LDS pass across the 8 waves; wave 0 does softmax/top-4/stores.

namespace {
constexpr int TOKENS = 16384;
constexpr int DIM    = 6144;
constexpr int NE     = 16;
constexpr int TOPK   = 4;
constexpr int WAVES  = 8;
constexpr int T_TILE = 64;
constexpr int KS     = DIM / WAVES;      // 768
constexpr int DC     = 16;               // d per chunk
constexpr int NCHUNK = KS / DC;          // 48 (even)
constexpr int RPAD   = 20;               // red-buffer token stride (floats): 16B-aligned
constexpr int TOPW_OFF = TOKENS * NE;
constexpr int EXP_OFF  = TOPW_OFF + TOKENS * TOPK;
}

__device__ __forceinline__ void fma16(float xs, const float4& w0, const float4& w1,
                                      const float4& w2, const float4& w3,
                                      float (&ac)[NE]) {
    ac[0]  = fmaf(xs, w0.x, ac[0]);  ac[1]  = fmaf(xs, w0.y, ac[1]);
    ac[2]  = fmaf(xs, w0.z, ac[2]);  ac[3]  = fmaf(xs, w0.w, ac[3]);
    ac[4]  = fmaf(xs, w1.x, ac[4]);  ac[5]  = fmaf(xs, w1.y, ac[5]);
    ac[6]  = fmaf(xs, w1.z, ac[6]);  ac[7]  = fmaf(xs, w1.w, ac[7]);
    ac[8]  = fmaf(xs, w2.x, ac[8]);  ac[9]  = fmaf(xs, w2.y, ac[9]);
    ac[10] = fmaf(xs, w2.z, ac[10]); ac[11] = fmaf(xs, w2.w, ac[11]);
    ac[12] = fmaf(xs, w3.x, ac[12]); ac[13] = fmaf(xs, w3.y, ac[13]);
    ac[14] = fmaf(xs, w3.z, ac[14]); ac[15] = fmaf(xs, w3.w, ac[15]);
}

__global__ __launch_bounds__(WAVES * 64, 2) void router_fused_kernel(
    const float* __restrict__ x, const float* __restrict__ W,
    float* __restrict__ out)
{
    __shared__ float red[WAVES][T_TILE][RPAD];   // 40 KB, epilogue only

    const int tid  = threadIdx.x;
    const int lane = tid & 63;
    const int wv   = tid >> 6;
    const int t0   = blockIdx.x * T_TILE;
    const int d0   = wv * KS;
    const int r    = lane >> 2;          // token row 0..15
    const int m    = lane & 3;           // d-quad 0..3

    const float* xb = x + (size_t)(t0 + r) * DIM + d0 + m * 4;
    const float* wb = W + (size_t)(d0 + m * 4) * NE;

    float acc[4][NE];
    #pragma unroll
    for (int it = 0; it < 4; ++it)
        #pragma unroll
        for (int e = 0; e < NE; ++e) acc[it][e] = 0.f;

    float4 xA[4], xB[4];     // x double buffer: [it]
    float4 wA[16], wB[16];   // W double buffer: [j*4+q] = row 4m+j, cols 4q..4q+3

    // prologue: chunk 0 into A
    #pragma unroll
    for (int it = 0; it < 4; ++it)
        xA[it] = *reinterpret_cast<const float4*>(xb + (size_t)(16 * it) * DIM);
    #pragma unroll
    for (int j = 0; j < 4; ++j)
        #pragma unroll
        for (int q = 0; q < 4; ++q)
            wA[j * 4 + q] = *reinterpret_cast<const float4*>(wb + j * NE + q * 4);

    #pragma unroll 1
    for (int c = 0; c < NCHUNK; c += 2) {
        // load chunk c+1 into B
        {
            const float* xp = xb + (c + 1) * DC;
            const float* wp = wb + (size_t)(c + 1) * DC * NE;
            #pragma unroll
            for (int it = 0; it < 4; ++it)
                xB[it] = *reinterpret_cast<const float4*>(xp + (size_t)(16 * it) * DIM);
            #pragma unroll
            for (int j = 0; j < 4; ++j)
                #pragma unroll
                for (int q = 0; q < 4; ++q)
                    wB[j * 4 + q] = *reinterpret_cast<const float4*>(wp + j * NE + q * 4);
        }
        // compute chunk c from A
        #pragma unroll
        for (int it = 0; it < 4; ++it) {
            const float4 xv = xA[it];
            fma16(xv.x, wA[0],  wA[1],  wA[2],  wA[3],  acc[it]);
            fma16(xv.y, wA[4],  wA[5],  wA[6],  wA[7],  acc[it]);
            fma16(xv.z, wA[8],  wA[9],  wA[10], wA[11], acc[it]);
            fma16(xv.w, wA[12], wA[13], wA[14], wA[15], acc[it]);
        }
        // load chunk c+2 into A
        if (c + 2 < NCHUNK) {
            const float* xp = xb + (c + 2) * DC;
            const float* wp = wb + (size_t)(c + 2) * DC * NE;
            #pragma unroll
            for (int it = 0; it < 4; ++it)
                xA[it] = *reinterpret_cast<const float4*>(xp + (size_t)(16 * it) * DIM);
            #pragma unroll
            for (int j = 0; j < 4; ++j)
                #pragma unroll
                for (int q = 0; q < 4; ++q)
                    wA[j * 4 + q] = *reinterpret_cast<const float4*>(wp + j * NE + q * 4);
        }
        // compute chunk c+1 from B
        #pragma unroll
        for (int it = 0; it < 4; ++it) {
            const float4 xv = xB[it];
            fma16(xv.x, wB[0],  wB[1],  wB[2],  wB[3],  acc[it]);
            fma16(xv.y, wB[4],  wB[5],  wB[6],  wB[7],  acc[it]);
            fma16(xv.z, wB[8],  wB[9],  wB[10], wB[11], acc[it]);
            fma16(xv.w, wB[12], wB[13], wB[14], wB[15], acc[it]);
        }
    }

    // ---- reduce over m within 4-lane groups (full sum lands in all 4 lanes) ----
    #pragma unroll
    for (int it = 0; it < 4; ++it)
        #pragma unroll
        for (int e = 0; e < NE; ++e) {
            float v = acc[it][e];
            v += __shfl_xor(v, 1, 64);
            v += __shfl_xor(v, 2, 64);
            acc[it][e] = v;
        }

    // lane (r,m) writes token r+16*m (i.e. selects it == m; static select chain)
    {
        const int tok = r + 16 * m;
        float mine[NE];
        #pragma unroll
        for (int e = 0; e < NE; ++e) {
            float v = acc[0][e];
            v = (m == 1) ? acc[1][e] : v;
            v = (m == 2) ? acc[2][e] : v;
            v = (m == 3) ? acc[3][e] : v;
            mine[e] = v;
        }
        #pragma unroll
        for (int q = 0; q < 4; ++q)
            *reinterpret_cast<float4*>(&red[wv][tok][4 * q]) =
                make_float4(mine[4 * q], mine[4 * q + 1], mine[4 * q + 2], mine[4 * q + 3]);
    }
    __syncthreads();

    // ---- wave 0: cross-wave reduce + softmax + top-4 + stores ----
    if (tid < T_TILE) {
        const int t = tid;
        float l[NE];
        #pragma unroll
        for (int e = 0; e < NE; ++e) {
            float s = red[0][t][e];
            #pragma unroll
            for (int w = 1; w < WAVES; ++w) s += red[w][t][e];
            l[e] = s;
        }
        float mx = l[0];
        #pragma unroll
        for (int e = 1; e < NE; ++e) mx = fmaxf(mx, l[e]);
        float w[NE];
        float sum = 0.f;
        #pragma unroll
        for (int e = 0; e < NE; ++e) { w[e] = expf(l[e] - mx); sum += w[e]; }
        const float inv = 1.f / sum;
        #pragma unroll
        for (int e = 0; e < NE; ++e) w[e] *= inv;

        // stable top-4: strict '>' keeps lowest index on ties (matches jax.lax.top_k)
        int   idx[TOPK];
        float tw[TOPK];
        unsigned used = 0;
        #pragma unroll
        for (int k = 0; k < TOPK; ++k) {
            float best = -1.f;
            int   bi   = 0;
            #pragma unroll
            for (int e = 0; e < NE; ++e) {
                const bool avail = ((used >> e) & 1u) == 0u;
                if (avail && w[e] > best) { best = w[e]; bi = e; }
            }
            used |= (1u << bi);
            idx[k] = bi;
            tw[k]  = best;
        }
        const float s4 = tw[0] + tw[1] + tw[2] + tw[3];
        const float rinv = 1.f / s4;

        const int tt = t0 + t;
        float4* o0 = reinterpret_cast<float4*>(out + (size_t)tt * NE);
        o0[0] = make_float4(w[0], w[1], w[2], w[3]);
        o0[1] = make_float4(w[4], w[5], w[6], w[7]);
        o0[2] = make_float4(w[8], w[9], w[10], w[11]);
        o0[3] = make_float4(w[12], w[13], w[14], w[15]);
        *reinterpret_cast<float4*>(out + TOPW_OFF + (size_t)tt * TOPK) =
            make_float4(tw[0] * rinv, tw[1] * rinv, tw[2] * rinv, tw[3] * rinv);
        *reinterpret_cast<float4*>(out + EXP_OFF + (size_t)tt * TOPK) =
            make_float4((float)idx[0], (float)idx[1], (float)idx[2], (float)idx[3]);
    }
}

extern "C" void kernel_launch(void* const* d_in, const int* in_sizes, int n_in,
                              void* d_out, int out_size, void* d_ws, size_t ws_size,
                              hipStream_t stream) {
    const float* x = (const float*)d_in[0];
    const float* W = (const float*)d_in[1];
    float* out = (float*)d_out;
    (void)d_ws; (void)ws_size;

    router_fused_kernel<<<TOKENS / T_TILE, WAVES * 64, 0, stream>>>(x, W, out);
}

// Round 5
// 172.514 us; speedup vs baseline: 2.8611x; 2.8611x over previous
//
#include <hip/hip_runtime.h>
#include <cmath>

// DBRX router, fused single kernel.
// logits = x[16384,6144] @ W[6144,16]; softmax; top-4; L1-normalize.
// Outputs flat: weights fp32[16384*16] | top_weights fp32[16384*4] | experts(as float)[16384*4]
//
// Block = 8 waves = 64 tokens (lane = token). Wave wv owns d-slice [wv*768,(wv+1)*768).
// x: coalesced float4 loads (depth-2 chunk pipeline) -> per-wave-private LDS transpose
//    (no barriers in main loop; same-wave DS ops are ordered).
// W: addresses made wave-uniform via readfirstlane -> compiler can select s_load;
//    W operand then rides in SGPRs, costing zero LDS/VGPR bandwidth in the FMA loop.
// Epilogue: LDS reduce across the 8 waves (buffer overlaid on stage, barrier-separated),
// wave 0 does softmax/top-4/L1-normalize/stores.

namespace {
constexpr int TOKENS = 16384;
constexpr int DIM    = 6144;
constexpr int NE     = 16;
constexpr int TOPK   = 4;
constexpr int WAVES  = 8;
constexpr int T_TILE = 64;
constexpr int KS     = DIM / WAVES;      // 768
constexpr int DC     = 16;               // d per chunk
constexpr int NCHUNK = KS / DC;          // 48
constexpr int XPAD   = 66;               // stage token-stride: <=2-way bank alias (free)
constexpr int RPAD   = 20;               // reduce-buffer token stride (80B, 16B-aligned)
constexpr int TOPW_OFF = TOKENS * NE;
constexpr int EXP_OFF  = TOPW_OFF + TOKENS * TOPK;
}

__device__ __forceinline__ void fma16(float xs, const float4& w0, const float4& w1,
                                      const float4& w2, const float4& w3,
                                      float (&ac)[NE]) {
    ac[0]  = fmaf(xs, w0.x, ac[0]);  ac[1]  = fmaf(xs, w0.y, ac[1]);
    ac[2]  = fmaf(xs, w0.z, ac[2]);  ac[3]  = fmaf(xs, w0.w, ac[3]);
    ac[4]  = fmaf(xs, w1.x, ac[4]);  ac[5]  = fmaf(xs, w1.y, ac[5]);
    ac[6]  = fmaf(xs, w1.z, ac[6]);  ac[7]  = fmaf(xs, w1.w, ac[7]);
    ac[8]  = fmaf(xs, w2.x, ac[8]);  ac[9]  = fmaf(xs, w2.y, ac[9]);
    ac[10] = fmaf(xs, w2.z, ac[10]); ac[11] = fmaf(xs, w2.w, ac[11]);
    ac[12] = fmaf(xs, w3.x, ac[12]); ac[13] = fmaf(xs, w3.y, ac[13]);
    ac[14] = fmaf(xs, w3.z, ac[14]); ac[15] = fmaf(xs, w3.w, ac[15]);
}

__global__ __launch_bounds__(WAVES * 64) void router_fused_kernel(
    const float* __restrict__ x, const float* __restrict__ W,
    float* __restrict__ out)
{
    // overlay: x-stage (8448 floats) under reduce buffer (10240 floats) = 40.96 KB
    __shared__ float smem[WAVES * T_TILE * RPAD];
    float (*xstage)[DC][XPAD] = reinterpret_cast<float(*)[DC][XPAD]>(smem);
    float (*red)[T_TILE][RPAD] = reinterpret_cast<float(*)[T_TILE][RPAD]>(smem);

    const int tid  = threadIdx.x;
    const int lane = tid & 63;
    const int wv   = tid >> 6;
    const int t0   = blockIdx.x * T_TILE;
    const int d0   = wv * KS;
    const int m    = lane & 3;            // float4 slot within 16-d chunk
    const int r0   = lane >> 2;           // token row base (0..15)

    const float* xb = x + (size_t)(t0 + r0) * DIM + d0 + m * 4;
    // wave-uniform W base: readfirstlane makes d0 provably uniform -> s_load path
    const int d0u = __builtin_amdgcn_readfirstlane(d0);
    const float* wb = W + (size_t)d0u * NE;

    float acc[NE];
    #pragma unroll
    for (int e = 0; e < NE; ++e) acc[e] = 0.f;

    float4 v0[4], v1[4], v2[4];
    // prologue: chunks 0,1 in flight
    #pragma unroll
    for (int it = 0; it < 4; ++it)
        v0[it] = *reinterpret_cast<const float4*>(xb + (size_t)(16 * it) * DIM);
    #pragma unroll
    for (int it = 0; it < 4; ++it)
        v1[it] = *reinterpret_cast<const float4*>(xb + (size_t)(16 * it) * DIM + DC);

    #pragma unroll 2
    for (int c = 0; c < NCHUNK; ++c) {
        // stage chunk c into this wave's private LDS region (transposed)
        #pragma unroll
        for (int it = 0; it < 4; ++it) {
            const int r = r0 + 16 * it;
            const int d = m * 4;
            xstage[wv][d + 0][r] = v0[it].x;
            xstage[wv][d + 1][r] = v0[it].y;
            xstage[wv][d + 2][r] = v0[it].z;
            xstage[wv][d + 3][r] = v0[it].w;
        }
        // issue chunk c+2 loads (in flight under this chunk's compute)
        if (c + 2 < NCHUNK) {
            #pragma unroll
            for (int it = 0; it < 4; ++it)
                v2[it] = *reinterpret_cast<const float4*>(
                    xb + (size_t)(16 * it) * DIM + (size_t)(c + 2) * DC);
        }
        // compute: x from LDS (lane-consecutive b32, conflict-free);
        // W from wave-uniform address (SGPR operand in v_fma)
        const float* wp = wb + (size_t)c * DC * NE;
        #pragma unroll
        for (int dd = 0; dd < DC; ++dd) {
            const float xv = xstage[wv][dd][lane];
            const float4 w0 = *reinterpret_cast<const float4*>(wp + dd * NE + 0);
            const float4 w1 = *reinterpret_cast<const float4*>(wp + dd * NE + 4);
            const float4 w2 = *reinterpret_cast<const float4*>(wp + dd * NE + 8);
            const float4 w3 = *reinterpret_cast<const float4*>(wp + dd * NE + 12);
            fma16(xv, w0, w1, w2, w3, acc);
        }
        #pragma unroll
        for (int it = 0; it < 4; ++it) { v0[it] = v1[it]; v1[it] = v2[it]; }
    }

    // ---- cross-wave reduce + epilogue ----
    __syncthreads();   // all waves done with xstage before overlay reuse
    #pragma unroll
    for (int q = 0; q < 4; ++q)
        *reinterpret_cast<float4*>(&red[wv][lane][4 * q]) =
            make_float4(acc[4 * q], acc[4 * q + 1], acc[4 * q + 2], acc[4 * q + 3]);
    __syncthreads();   // partials visible

    if (tid < T_TILE) {
        const int t = tid;
        float l[NE];
        #pragma unroll
        for (int e = 0; e < NE; ++e) {
            float s = red[0][t][e];
            #pragma unroll
            for (int w = 1; w < WAVES; ++w) s += red[w][t][e];
            l[e] = s;
        }
        // softmax (max-subtracted, like jax.nn.softmax)
        float mx = l[0];
        #pragma unroll
        for (int e = 1; e < NE; ++e) mx = fmaxf(mx, l[e]);
        float w[NE];
        float sum = 0.f;
        #pragma unroll
        for (int e = 0; e < NE; ++e) { w[e] = expf(l[e] - mx); sum += w[e]; }
        const float inv = 1.f / sum;
        #pragma unroll
        for (int e = 0; e < NE; ++e) w[e] *= inv;

        // stable top-4: strict '>' keeps lowest index on ties (matches jax.lax.top_k)
        int   idx[TOPK];
        float tw[TOPK];
        unsigned used = 0;
        #pragma unroll
        for (int k = 0; k < TOPK; ++k) {
            float best = -1.f;
            int   bi   = 0;
            #pragma unroll
            for (int e = 0; e < NE; ++e) {
                const bool avail = ((used >> e) & 1u) == 0u;
                if (avail && w[e] > best) { best = w[e]; bi = e; }
            }
            used |= (1u << bi);
            idx[k] = bi;
            tw[k]  = best;
        }
        const float s4 = tw[0] + tw[1] + tw[2] + tw[3];
        const float rinv = 1.f / s4;

        const int tt = t0 + t;
        float4* o0 = reinterpret_cast<float4*>(out + (size_t)tt * NE);
        o0[0] = make_float4(w[0], w[1], w[2], w[3]);
        o0[1] = make_float4(w[4], w[5], w[6], w[7]);
        o0[2] = make_float4(w[8], w[9], w[10], w[11]);
        o0[3] = make_float4(w[12], w[13], w[14], w[15]);
        *reinterpret_cast<float4*>(out + TOPW_OFF + (size_t)tt * TOPK) =
            make_float4(tw[0] * rinv, tw[1] * rinv, tw[2] * rinv, tw[3] * rinv);
        *reinterpret_cast<float4*>(out + EXP_OFF + (size_t)tt * TOPK) =
            make_float4((float)idx[0], (float)idx[1], (float)idx[2], (float)idx[3]);
    }
}

extern "C" void kernel_launch(void* const* d_in, const int* in_sizes, int n_in,
                              void* d_out, int out_size, void* d_ws, size_t ws_size,
                              hipStream_t stream) {
    const float* x = (const float*)d_in[0];
    const float* W = (const float*)d_in[1];
    float* out = (float*)d_out;
    (void)d_ws; (void)ws_size;

    router_fused_kernel<<<TOKENS / T_TILE, WAVES * 64, 0, stream>>>(x, W, out);
}